// Round 1
// 360.270 us; speedup vs baseline: 1.0173x; 1.0173x over previous
//
#include <hip/hip_runtime.h>
#include <hip/hip_fp16.h>
#include <cstdint>
#include <cstddef>

#define NN 50000
#define NE 800000
#define RNG 8
#define RSZ ((NN + RNG - 1) / RNG)
#define CPR 128

typedef _Float16 half8 __attribute__((ext_vector_type(8)));
typedef float    f32x4 __attribute__((ext_vector_type(4)));

static __device__ __forceinline__ float lrelu02(float x){ return x > 0.f ? x : 0.2f*x; }

static __device__ __forceinline__ float2 h2f(uint32_t u){
  __half2 h = *reinterpret_cast<__half2*>(&u);
  return __half22float2(h);
}
static __device__ __forceinline__ uint32_t f2h(float a, float b){
  __half2 h = __floats2half2_rn(a, b);
  return *reinterpret_cast<uint32_t*>(&h);
}

// ---------------- CSR preprocessing (range-partitioned, XCD-swizzled) ----------------
__global__ __launch_bounds__(256) void count_kernel(const int* __restrict__ dst,
                                                    int* __restrict__ cnt, int E){
  const int r  = blockIdx.x % RNG;
  const int i  = blockIdx.x / RNG;
  const int lo = r * RSZ;
  const int hi = min(lo + RSZ, NN);
  const int cs = (E + CPR - 1) / CPR;
  const int e1 = min((i+1)*cs, E);
  for (int e = i*cs + threadIdx.x; e < e1; e += 256){
    const int d = dst[e];
    if (d >= lo && d < hi) atomicAdd(&cnt[d], 1);
  }
}

__global__ __launch_bounds__(1024) void scan1_kernel(const int* __restrict__ cnt,
      int* __restrict__ incl, int* __restrict__ bsum, int N){
  __shared__ int tmp[1024];
  const int t = threadIdx.x;
  const int i = blockIdx.x*1024 + t;
  int v = (i < N) ? cnt[i] : 0;
  tmp[t] = v;
  __syncthreads();
  #pragma unroll
  for (int off = 1; off < 1024; off <<= 1){
    int u = (t >= off) ? tmp[t-off] : 0;
    __syncthreads();
    tmp[t] += u;
    __syncthreads();
  }
  if (i < N) incl[i] = tmp[t];
  if (t == 1023) bsum[blockIdx.x] = tmp[t];
}

__global__ void scan2_kernel(int* __restrict__ bsum, int NB){
  const int t = threadIdx.x;
  int own = (t < NB) ? bsum[t] : 0;
  int v = own;
  #pragma unroll
  for (int off = 1; off < 64; off <<= 1){
    int u = __shfl_up(v, off, 64);
    if (t >= off) v += u;
  }
  if (t < NB) bsum[t] = v - own;
}

__global__ void scan3_kernel(const int* __restrict__ cnt, const int* __restrict__ incl,
      const int* __restrict__ bsum, int* __restrict__ rp, int* __restrict__ fillp,
      float* __restrict__ dinv, int N){
  const int i = blockIdx.x*blockDim.x + threadIdx.x;
  if (i >= N) return;
  const int c = cnt[i];
  const int e = bsum[i >> 10] + incl[i] - c;
  rp[i] = e; fillp[i] = e;
  dinv[i] = rsqrtf((float)(c + 1));
  if (i == N-1) rp[N] = e + c;
}

__global__ __launch_bounds__(256) void fill_kernel(const int* __restrict__ src,
      const int* __restrict__ dst, int* __restrict__ fillp,
      int* __restrict__ col, int E){
  const int r  = blockIdx.x % RNG;
  const int i  = blockIdx.x / RNG;
  const int lo = r * RSZ;
  const int hi = min(lo + RSZ, NN);
  const int cs = (E + CPR - 1) / CPR;
  const int e1 = min((i+1)*cs, E);
  for (int e = i*cs + threadIdx.x; e < e1; e += 256){
    const int d = dst[e];
    if (d >= lo && d < hi){
      const int s = src[e];
      const int pos = atomicAdd(&fillp[d], 1);
      col[pos] = s;
    }
  }
}

// ---------------- MFMA f16 GEMM: C[MxN] = A[MxK] @ B[KxN] (+bias, *rowscale) ----------
// NEW STRUCTURE: whole B tile (K x 64, K<=192) staged to LDS ONCE (transposed, fp16),
// single __syncthreads, then barrier-free K-loop: A fragments loaded directly from
// global (16 rows x 128B contiguous per wave = coalesced), converted in-register.
// K is a template parameter -> full unroll, constant ds_read offsets, pipelined loads.
// Fragment layouts identical to verified kernel: A[m=lane&15][k=quad*8+j];
// B[k=quad*8+j][n=lane&15]; C/D: col=lane&15, row=quad*4+reg.
template<int K, bool HALF_OUT>
__global__ __launch_bounds__(256) void gemm_mfma_kernel(
    const float* __restrict__ A, const float* __restrict__ B,
    const float* __restrict__ bias, const float* __restrict__ rowscale,
    void* __restrict__ Cv, int M, int N)
{
  constexpr int LDK = K + 8;            // halves; row stride = 2*LDK bytes (16B mult, 2-way-free banks)
  __shared__ __align__(16) _Float16 Bt[64][LDK];   // Bt[n][k]
  const int bm = blockIdx.x * 64;
  const int bn = blockIdx.y * 64;
  const int t  = threadIdx.x;
  const int w    = t >> 6;
  const int lane = t & 63;
  const int m    = lane & 15;
  const int quad = lane >> 4;

  // stage B-tile transposed: float4 reads along n (coalesced), scalar LDS writes
  #pragma unroll
  for (int i = t; i < K*16; i += 256){
    const int k  = i >> 4;
    const int n4 = (i & 15) << 2;
    const float4 v = *(const float4*)(B + (size_t)k*N + bn + n4);
    Bt[n4+0][k] = (_Float16)v.x;
    Bt[n4+1][k] = (_Float16)v.y;
    Bt[n4+2][k] = (_Float16)v.z;
    Bt[n4+3][k] = (_Float16)v.w;
  }

  f32x4 acc[4];
  #pragma unroll
  for (int ct = 0; ct < 4; ++ct) acc[ct] = (f32x4){0.f,0.f,0.f,0.f};

  const int row = bm + w*16 + m;
  const float* Arow = A + (size_t)row*K;
  __syncthreads();

  #pragma unroll
  for (int k0 = 0; k0 < K; k0 += 32){
    union { half8 h; uint32_t u[4]; } ua;
    if (row < M){
      const float4 va = *(const float4*)(Arow + k0 + quad*8);
      const float4 vb = *(const float4*)(Arow + k0 + quad*8 + 4);
      ua.u[0] = f2h(va.x, va.y);
      ua.u[1] = f2h(va.z, va.w);
      ua.u[2] = f2h(vb.x, vb.y);
      ua.u[3] = f2h(vb.z, vb.w);
    } else {
      ua.u[0] = ua.u[1] = ua.u[2] = ua.u[3] = 0u;
    }
    const half8 af = ua.h;
    #pragma unroll
    for (int ct = 0; ct < 4; ++ct){
      const half8 bf = *(const half8*)&Bt[ct*16 + m][k0 + quad*8];
      acc[ct] = __builtin_amdgcn_mfma_f32_16x16x32_f16(af, bf, acc[ct], 0, 0, 0);
    }
  }

  // epilogue: C[row=bm+16w+4*quad+reg][col=bn+16ct+m]
  float rs[4];
  #pragma unroll
  for (int reg = 0; reg < 4; ++reg){
    const int r = bm + w*16 + quad*4 + reg;
    rs[reg] = (rowscale && r < M) ? rowscale[r] : 1.f;
  }
  #pragma unroll
  for (int ct = 0; ct < 4; ++ct){
    const int colg = bn + ct*16 + m;
    const float bv = bias ? bias[colg] : 0.f;
    #pragma unroll
    for (int reg = 0; reg < 4; ++reg){
      const int r = bm + w*16 + quad*4 + reg;
      if (r < M){
        const float v = rs[reg]*acc[ct][reg] + bv;
        if constexpr (HALF_OUT){
          ((__half*)Cv)[(size_t)r*N + colg] = __float2half(v);
        } else {
          ((float*)Cv)[(size_t)r*N + colg] = v;
        }
      }
    }
  }
}

// ---------------- GCN aggregation F=128 over pre-scaled fp16 H' (H'=dinv*H) ----------
// 4 groups of 16 lanes, each group gathers one full 256B row via dwordx4 -> 4 rows/step.
__global__ __launch_bounds__(256) void gcn_agg128_kernel(
    const __half* __restrict__ H, const int* __restrict__ rp, const int* __restrict__ col,
    const float* __restrict__ dinv, const float* __restrict__ bias,
    float* __restrict__ out, int N)
{
  const int n    = blockIdx.x * (blockDim.x >> 6) + (threadIdx.x >> 6);
  const int lane = threadIdx.x & 63;
  const int g    = lane >> 4;
  const int gl   = lane & 15;
  if (n >= N) return;
  const float dn = dinv[n];
  f32x4 accA = (f32x4){0.f,0.f,0.f,0.f};
  f32x4 accB = (f32x4){0.f,0.f,0.f,0.f};
  if (g == 0){
    uint4 raw = *(const uint4*)(H + (size_t)n*128 + gl*8);
    float2 f0=h2f(raw.x), f1=h2f(raw.y), f2=h2f(raw.z), f3=h2f(raw.w);
    accA = (f32x4){f0.x, f0.y, f1.x, f1.y};
    accB = (f32x4){f2.x, f2.y, f3.x, f3.y};
  }
  const int s0 = rp[n], s1 = rp[n+1];
  for (int c0 = s0; c0 < s1; c0 += 64){
    const int nc = min(64, s1 - c0);
    int sl = (lane < nc) ? col[c0 + lane] : 0;
    const int nt = (nc + 3) >> 2;
    #pragma unroll 4
    for (int tstep = 0; tstep < nt; ++tstep){
      const int j = 4*tstep + g;
      const int s = __shfl(sl, j, 64);
      if (j < nc){
        uint4 raw = *(const uint4*)(H + (size_t)s*128 + gl*8);
        float2 f0=h2f(raw.x), f1=h2f(raw.y), f2=h2f(raw.z), f3=h2f(raw.w);
        accA.x += f0.x; accA.y += f0.y; accA.z += f1.x; accA.w += f1.y;
        accB.x += f2.x; accB.y += f2.y; accB.z += f3.x; accB.w += f3.y;
      }
    }
  }
  #pragma unroll
  for (int off = 32; off >= 16; off >>= 1){
    accA.x += __shfl_down(accA.x, off, 64); accA.y += __shfl_down(accA.y, off, 64);
    accA.z += __shfl_down(accA.z, off, 64); accA.w += __shfl_down(accA.w, off, 64);
    accB.x += __shfl_down(accB.x, off, 64); accB.y += __shfl_down(accB.y, off, 64);
    accB.z += __shfl_down(accB.z, off, 64); accB.w += __shfl_down(accB.w, off, 64);
  }
  if (g == 0){
    float4 b0 = *(const float4*)(bias + gl*8);
    float4 b1 = *(const float4*)(bias + gl*8 + 4);
    float4 o0, o1;
    o0.x = dn*accA.x + b0.x; o0.y = dn*accA.y + b0.y;
    o0.z = dn*accA.z + b0.z; o0.w = dn*accA.w + b0.w;
    o1.x = dn*accB.x + b1.x; o1.y = dn*accB.y + b1.y;
    o1.z = dn*accB.z + b1.z; o1.w = dn*accB.w + b1.w;
    *(float4*)(out + (size_t)n*128 + gl*8)     = o0;
    *(float4*)(out + (size_t)n*128 + gl*8 + 4) = o1;
  }
}

// ---------------- GCN aggregation F=64 over pre-scaled fp16 H' ----------
// 8 groups of 8 lanes, each group gathers one full 128B row via dwordx4 -> 8 rows/step.
__global__ __launch_bounds__(256) void gcn_agg64_kernel(
    const __half* __restrict__ H, const int* __restrict__ rp, const int* __restrict__ col,
    const float* __restrict__ dinv, const float* __restrict__ bias,
    float* __restrict__ out, int N)
{
  const int n    = blockIdx.x * (blockDim.x >> 6) + (threadIdx.x >> 6);
  const int lane = threadIdx.x & 63;
  const int g    = lane >> 3;
  const int gl   = lane & 7;
  if (n >= N) return;
  const float dn = dinv[n];
  f32x4 accA = (f32x4){0.f,0.f,0.f,0.f};
  f32x4 accB = (f32x4){0.f,0.f,0.f,0.f};
  if (g == 0){
    uint4 raw = *(const uint4*)(H + (size_t)n*64 + gl*8);
    float2 f0=h2f(raw.x), f1=h2f(raw.y), f2=h2f(raw.z), f3=h2f(raw.w);
    accA = (f32x4){f0.x, f0.y, f1.x, f1.y};
    accB = (f32x4){f2.x, f2.y, f3.x, f3.y};
  }
  const int s0 = rp[n], s1 = rp[n+1];
  for (int c0 = s0; c0 < s1; c0 += 64){
    const int nc = min(64, s1 - c0);
    int sl = (lane < nc) ? col[c0 + lane] : 0;
    const int nt = (nc + 7) >> 3;
    #pragma unroll 4
    for (int tstep = 0; tstep < nt; ++tstep){
      const int j = 8*tstep + g;
      const int s = __shfl(sl, j, 64);
      if (j < nc){
        uint4 raw = *(const uint4*)(H + (size_t)s*64 + gl*8);
        float2 f0=h2f(raw.x), f1=h2f(raw.y), f2=h2f(raw.z), f3=h2f(raw.w);
        accA.x += f0.x; accA.y += f0.y; accA.z += f1.x; accA.w += f1.y;
        accB.x += f2.x; accB.y += f2.y; accB.z += f3.x; accB.w += f3.y;
      }
    }
  }
  #pragma unroll
  for (int off = 32; off >= 8; off >>= 1){
    accA.x += __shfl_down(accA.x, off, 64); accA.y += __shfl_down(accA.y, off, 64);
    accA.z += __shfl_down(accA.z, off, 64); accA.w += __shfl_down(accA.w, off, 64);
    accB.x += __shfl_down(accB.x, off, 64); accB.y += __shfl_down(accB.y, off, 64);
    accB.z += __shfl_down(accB.z, off, 64); accB.w += __shfl_down(accB.w, off, 64);
  }
  if (g == 0){
    float4 b0 = *(const float4*)(bias + gl*8);
    float4 b1 = *(const float4*)(bias + gl*8 + 4);
    float4 o0, o1;
    o0.x = dn*accA.x + b0.x; o0.y = dn*accA.y + b0.y;
    o0.z = dn*accA.z + b0.z; o0.w = dn*accA.w + b0.w;
    o1.x = dn*accB.x + b1.x; o1.y = dn*accB.y + b1.y;
    o1.z = dn*accB.z + b1.z; o1.w = dn*accB.w + b1.w;
    *(float4*)(out + (size_t)n*64 + gl*8)     = o0;
    *(float4*)(out + (size_t)n*64 + gl*8 + 4) = o1;
  }
}

// ---------------- al/ar = HG @ a_src, HG @ a_dst (HG in fp16) ----------------
__global__ __launch_bounds__(256) void alar_kernel(const __half* __restrict__ HG,
    const float* __restrict__ a_src, const float* __restrict__ a_dst,
    float* __restrict__ al, float* __restrict__ ar, int N)
{
  const int n    = blockIdx.x * (blockDim.x >> 6) + (threadIdx.x >> 6);
  const int lane = threadIdx.x & 63;
  if (n >= N) return;
  uint32_t raw = *(const uint32_t*)(HG + (size_t)n*128 + lane*2);
  float2 h  = h2f(raw);
  float2 as = *(const float2*)(a_src + lane*2);
  float2 ad = *(const float2*)(a_dst + lane*2);
  float s = h.x*as.x + h.y*as.y;
  float d = h.x*ad.x + h.y*ad.y;
  #pragma unroll
  for (int off = 32; off > 0; off >>= 1){
    s += __shfl_down(s, off, 64);
    d += __shfl_down(d, off, 64);
  }
  if (lane == 0){ al[n] = s; ar[n] = d; }
}

// ---------------- GAT aggregation: shift-free softmax + quarter-wave fp16 gather -----
__global__ __launch_bounds__(256) void gat_agg_kernel(
    const __half* __restrict__ HG, const int* __restrict__ rp, const int* __restrict__ col,
    const float* __restrict__ al, const float* __restrict__ ar,
    const float* __restrict__ bias, float* __restrict__ out, int N)
{
  const int n    = blockIdx.x * (blockDim.x >> 6) + (threadIdx.x >> 6);
  const int lane = threadIdx.x & 63;
  const int g    = lane >> 4;
  const int gl   = lane & 15;
  if (n >= N) return;
  const float arn = ar[n];
  const float pself = __expf(lrelu02(al[n] + arn));
  float lpart = 0.f;
  f32x4 accA = (f32x4){0.f,0.f,0.f,0.f};
  f32x4 accB = (f32x4){0.f,0.f,0.f,0.f};
  if (g == 0){
    uint4 raw = *(const uint4*)(HG + (size_t)n*128 + gl*8);
    float2 f0=h2f(raw.x), f1=h2f(raw.y), f2=h2f(raw.z), f3=h2f(raw.w);
    accA = (f32x4){pself*f0.x, pself*f0.y, pself*f1.x, pself*f1.y};
    accB = (f32x4){pself*f2.x, pself*f2.y, pself*f3.x, pself*f3.y};
  }
  const int s0 = rp[n], s1 = rp[n+1];
  for (int c0 = s0; c0 < s1; c0 += 64){
    const int nc = min(64, s1 - c0);
    int   sl = (lane < nc) ? col[c0 + lane] : 0;
    float pl = (lane < nc) ? __expf(lrelu02(al[sl] + arn)) : 0.f;
    lpart += pl;
    const int nt = (nc + 3) >> 2;
    #pragma unroll 4
    for (int tstep = 0; tstep < nt; ++tstep){
      const int j = 4*tstep + g;
      const int   s = __shfl(sl, j, 64);
      const float p = __shfl(pl, j, 64);
      if (j < nc){
        uint4 raw = *(const uint4*)(HG + (size_t)s*128 + gl*8);
        float2 f0=h2f(raw.x), f1=h2f(raw.y), f2=h2f(raw.z), f3=h2f(raw.w);
        accA.x += p*f0.x; accA.y += p*f0.y; accA.z += p*f1.x; accA.w += p*f1.y;
        accB.x += p*f2.x; accB.y += p*f2.y; accB.z += p*f3.x; accB.w += p*f3.y;
      }
    }
  }
  #pragma unroll
  for (int off = 32; off > 0; off >>= 1) lpart += __shfl_xor(lpart, off, 64);
  const float l = pself + lpart;
  #pragma unroll
  for (int off = 32; off >= 16; off >>= 1){
    accA.x += __shfl_down(accA.x, off, 64); accA.y += __shfl_down(accA.y, off, 64);
    accA.z += __shfl_down(accA.z, off, 64); accA.w += __shfl_down(accA.w, off, 64);
    accB.x += __shfl_down(accB.x, off, 64); accB.y += __shfl_down(accB.y, off, 64);
    accB.z += __shfl_down(accB.z, off, 64); accB.w += __shfl_down(accB.w, off, 64);
  }
  if (g == 0){
    const float inv = 1.f / l;
    float4 b0 = *(const float4*)(bias + gl*8);
    float4 b1 = *(const float4*)(bias + gl*8 + 4);
    float4 o0, o1;
    o0.x = fmaxf(accA.x*inv + b0.x, 0.f);
    o0.y = fmaxf(accA.y*inv + b0.y, 0.f);
    o0.z = fmaxf(accA.z*inv + b0.z, 0.f);
    o0.w = fmaxf(accA.w*inv + b0.w, 0.f);
    o1.x = fmaxf(accB.x*inv + b1.x, 0.f);
    o1.y = fmaxf(accB.y*inv + b1.y, 0.f);
    o1.z = fmaxf(accB.z*inv + b1.z, 0.f);
    o1.w = fmaxf(accB.w*inv + b1.w, 0.f);
    *(float4*)(out + (size_t)n*128 + gl*8)     = o0;
    *(float4*)(out + (size_t)n*128 + gl*8 + 4) = o1;
  }
}

// ---------------- launch ----------------
extern "C" void kernel_launch(void* const* d_in, const int* in_sizes, int n_in,
                              void* d_out, int out_size, void* d_ws, size_t ws_size,
                              hipStream_t stream)
{
  const float* x     = (const float*)d_in[0];
  const int*   ei    = (const int*)d_in[1];
  const float* W1    = (const float*)d_in[2];
  const float* b1    = (const float*)d_in[3];
  const float* Wg    = (const float*)d_in[4];
  const float* a_src = (const float*)d_in[5];
  const float* a_dst = (const float*)d_in[6];
  const float* bg    = (const float*)d_in[7];
  const float* W2    = (const float*)d_in[8];
  const float* b2    = (const float*)d_in[9];
  const float* Wf    = (const float*)d_in[10];
  const float* bf    = (const float*)d_in[11];
  const int N = NN, E = NE;
  const int* src = ei;
  const int* dst = ei + E;

  char* p = (char*)d_ws;
  auto alloc = [&](size_t bytes)->char*{
    char* r = p; p += (bytes + 511) & ~size_t(511); return r;
  };
  int*    cnt   = (int*)   alloc((size_t)N*4);
  int*    incl  = (int*)   alloc((size_t)N*4);
  int*    bsum  = (int*)   alloc(64*4);
  int*    rp    = (int*)   alloc((size_t)(N+1)*4);
  int*    fillp = (int*)   alloc((size_t)N*4);
  int*    col   = (int*)   alloc((size_t)E*4);
  float*  dinv  = (float*) alloc((size_t)N*4);
  float*  al    = (float*) alloc((size_t)N*4);
  float*  ar    = (float*) alloc((size_t)N*4);
  __half* H16   = (__half*)alloc((size_t)N*128*2);
  float*  bufB  = (float*) alloc((size_t)N*128*4);

  const int NB = (N + 1023) / 1024;

  hipMemsetAsync(cnt, 0, (size_t)N*4, stream);
  count_kernel<<<RNG*CPR, 256, 0, stream>>>(dst, cnt, E);
  scan1_kernel<<<NB, 1024, 0, stream>>>(cnt, incl, bsum, N);
  scan2_kernel<<<1, 64, 0, stream>>>(bsum, NB);
  scan3_kernel<<<(N+255)/256, 256, 0, stream>>>(cnt, incl, bsum, rp, fillp, dinv, N);
  fill_kernel<<<RNG*CPR, 256, 0, stream>>>(src, dst, fillp, col, E);

  const int gm = (N + 63) / 64;
  const int ga = (N + 3) / 4;

  // GEMM1: H16 = fp16( dinv ⊙ (x @ W1) )  [K=192, N=128]
  gemm_mfma_kernel<192, true><<<dim3(gm, 2), 256, 0, stream>>>(x, W1, nullptr, dinv, H16, N, 128);
  // AGG1 (GCN): H16 -> bufB (+b1), fp32
  gcn_agg128_kernel<<<ga, 256, 0, stream>>>(H16, rp, col, dinv, b1, bufB, N);
  // GEMM2: H16 = fp16( bufB @ Wg )   (HG)  [K=128, N=128]
  gemm_mfma_kernel<128, true><<<dim3(gm, 2), 256, 0, stream>>>(bufB, Wg, nullptr, nullptr, H16, N, 128);
  // al/ar from fp16 HG
  alar_kernel<<<ga, 256, 0, stream>>>(H16, a_src, a_dst, al, ar, N);
  // GAT: H16 -> bufB (+bg, relu fused), fp32
  gat_agg_kernel<<<ga, 256, 0, stream>>>(H16, rp, col, al, ar, bg, bufB, N);
  // GEMM3: H16 = fp16( dinv ⊙ (bufB @ W2) )  [K=128, N=64]
  gemm_mfma_kernel<128, true><<<dim3(gm, 1), 256, 0, stream>>>(bufB, W2, nullptr, dinv, H16, N, 64);
  // AGG2 (GCN): H16 -> bufB (+b2), fp32, F=64
  gcn_agg64_kernel<<<ga, 256, 0, stream>>>(H16, rp, col, dinv, b2, bufB, N);
  // GEMM4: out = bufB @ Wf + bf (fp32)  [K=64, N=192]
  gemm_mfma_kernel<64, false><<<dim3(gm, 3), 256, 0, stream>>>(bufB, Wf, bf, nullptr, d_out, N, 192);
}